// Round 5
// baseline (150.309 us; speedup 1.0000x reference)
//
#include <hip/hip_runtime.h>
#include <hip/hip_bf16.h>
#include <math.h>

// EntropyInvarianceAttention: out = softmax(c * Q^T K) V^T per (b,h),
// c = ln(k_length[b]) / (8*ln(20)); q,k,v are (B, 512, 2048) fp32, l contiguous.
//
// R5: same data layouts as R4 (conflict-free, measured 0.92M) but latency-
// oriented execution shape:
//  - 128-thr blocks (2 waves), TQ=64, grid 1024 -> 4 independent blocks/CU
//    (R4 had 2 blocks/CU in one 4-wave barrier group -> 75% stall).
//    Independent 2-wave barrier groups fill each other's DMA/dep stalls.
//  - wave owns 32 q (2 column groups): every K/V LDS read feeds 2 MFMAs.
//  - P stays in registers (S^T C-layout == B-layout of 16x16x16 MFMA);
//    row-sums via ones-frag MFMA (keeps VALU pipe for exp2).
//  - double-buffered K/V via global_load_lds(16B), 1 barrier/iter.

typedef __attribute__((ext_vector_type(8))) short short8_t;
typedef __attribute__((ext_vector_type(4))) short short4_t;
typedef __attribute__((ext_vector_type(4))) float float4_t;

#define SEQ   2048
#define NBH   32
#define NKT   32

__device__ __forceinline__ unsigned f2bf2u(float a, float b) {
#if __has_builtin(__builtin_amdgcn_cvt_pk_bf16_f32)
  typedef __bf16 bf16x2_t __attribute__((ext_vector_type(2)));
  union { bf16x2_t v; unsigned u; } cv;
  cv.v = __builtin_amdgcn_cvt_pk_bf16_f32(a, b);
  return cv.u;
#else
  union { float f; unsigned u; } x, y;
  x.f = a; y.f = b;
  unsigned ra = x.u + 0x7fffu + ((x.u >> 16) & 1u);
  unsigned rb = y.u + 0x7fffu + ((y.u >> 16) & 1u);
  return (ra >> 16) | (rb & 0xffff0000u);
#endif
}

__device__ __forceinline__ short f2bf1(float a) {
  return (short)(f2bf2u(a, a) & 0xffffu);
}

__device__ __forceinline__ float fast_exp2(float x) {
#if __has_builtin(__builtin_amdgcn_exp2f)
  return __builtin_amdgcn_exp2f(x);
#else
  return exp2f(x);
#endif
}

__device__ __forceinline__ void gld16(const void* g, void* l) {
  __builtin_amdgcn_global_load_lds(
      (const __attribute__((address_space(1))) void*)g,
      (__attribute__((address_space(3))) void*)l, 16, 0, 0);
}

__device__ __forceinline__ float4_t mfma32(short8_t a, short8_t b, float4_t c) {
  return __builtin_amdgcn_mfma_f32_16x16x32_bf16(a, b, c, 0, 0, 0);
}

__device__ __forceinline__ float4_t mfma16(short4_t a, short4_t b, float4_t c) {
#if __has_builtin(__builtin_amdgcn_mfma_f32_16x16x16bf16_1k)
  return __builtin_amdgcn_mfma_f32_16x16x16bf16_1k(a, b, c, 0, 0, 0);
#else
  asm("v_mfma_f32_16x16x16_bf16 %0, %1, %2, %0" : "+v"(c) : "v"(a), "v"(b));
  return c;
#endif
}

// ---------------- fused pre-pass: K and V -> tile-blocked swizzled bf16 ----
// K -> Kt2[bh][kt][dc(8)][k(64)][8], V -> Vt2[bh][kt][k4(16)][d(64)][4].
// Tiles contiguous 8 KB; unchanged from R4 (layouts measured conflict-free).
#define PST 68
__global__ __launch_bounds__(256, 8)
void eia_prep_kernel(const float* __restrict__ kg, const float* __restrict__ vg,
                     unsigned short* __restrict__ Kt2, unsigned short* __restrict__ Vt2) {
  __shared__ __align__(16) short T[64 * PST];
  const int id  = blockIdx.x;
  const int isV = id >> 10;
  const int sub = id & 1023;
  const int bh  = sub >> 5;
  const int kt  = sub & 31;
  const int t   = threadIdx.x;

  if (!isV) {
    const size_t ib = ((size_t)bh * 64) * SEQ + (size_t)(kt * 64) + (t & 63);
    const int dg = t >> 6;
#pragma unroll
    for (int dd = 0; dd < 16; dd += 4) {
      const int d = dg * 16 + dd;
      const float f0 = kg[ib + (size_t)(d + 0) * SEQ];
      const float f1 = kg[ib + (size_t)(d + 1) * SEQ];
      const float f2 = kg[ib + (size_t)(d + 2) * SEQ];
      const float f3 = kg[ib + (size_t)(d + 3) * SEQ];
      union { short4_t s; unsigned u[2]; } p;
      p.u[0] = f2bf2u(f0, f1);
      p.u[1] = f2bf2u(f2, f3);
      *(short4_t*)&T[(t & 63) * PST + d] = p.s;
    }
    __syncthreads();
    unsigned short* outt = Kt2 + (size_t)(bh * 32 + kt) * 4096;
#pragma unroll
    for (int rep = 0; rep < 2; ++rep) {
      const int id2 = rep * 256 + t;
      const int lr = id2 & 63, ch = id2 >> 6;
      union { short8_t v; short4_t h[2]; } o;
      o.h[0] = *(const short4_t*)&T[lr * PST + ch * 8];
      o.h[1] = *(const short4_t*)&T[lr * PST + ch * 8 + 4];
      *(short8_t*)&outt[ch * 512 + lr * 8] = o.v;
    }
  } else {
#pragma unroll
    for (int rep = 0; rep < 4; ++rep) {
      const int id2 = rep * 256 + t;
      const int d = id2 >> 4, l4 = (id2 & 15) * 4;
      const float4_t f = *(const float4_t*)&vg[((size_t)bh * 64 + d) * SEQ + kt * 64 + l4];
      union { short4_t s; unsigned u[2]; } p;
      p.u[0] = f2bf2u(f[0], f[1]);
      p.u[1] = f2bf2u(f[2], f[3]);
      *(short4_t*)&T[d * PST + l4] = p.s;
    }
    __syncthreads();
    unsigned short* outt = Vt2 + (size_t)(bh * 32 + kt) * 4096;
#pragma unroll
    for (int rep = 0; rep < 2; ++rep) {
      const int c = rep * 256 + t;
      const int k4 = c >> 5, dp = c & 31;
      union { short8_t v; short4_t h[2]; } o;
      o.h[0] = *(const short4_t*)&T[(2 * dp) * PST + k4 * 4];
      o.h[1] = *(const short4_t*)&T[(2 * dp + 1) * PST + k4 * 4];
      *(short8_t*)&outt[k4 * 256 + dp * 8] = o.v;
    }
  }
}

// ---------------- main fused attention ----------------
// LDS (shorts): K par0 [0,4096) | K par1 [4096,8192)
//               V par0 [8192,12288) | V par1 [12288,16384)
// Q staging overlays [0, 4352) before the first DMA.
__global__ __launch_bounds__(128, 2)
void eia_attn_kernel(const float* __restrict__ qg,
                     const unsigned short* __restrict__ Kt2,
                     const unsigned short* __restrict__ Vt2,
                     const int* __restrict__ klen,
                     float* __restrict__ outg) {
  __shared__ __align__(16) short SM[16384];

  const int tid  = threadIdx.x;
  const int bh   = blockIdx.x & 31;   // XCD = bh%8; 1024 blocks = 4/CU
  const int qt   = blockIdx.x >> 5;
  const int q0   = qt * 64;
  const int w    = tid >> 6;          // wave 0..1
  const int lane = tid & 63;
  const int quad = lane >> 4;
  const int l16  = lane & 15;

  const float c = (1.4426950408889634f / (8.0f * 2.9957322735539909f)) *
                  logf((float)klen[bh >> 3]);
  const size_t qb = (size_t)bh * 64 * SEQ;

  // ---- Q stage: fp32 global -> SM[q][d] bf16 (stride 68), c folded ----
#pragma unroll
  for (int rep = 0; rep < 8; ++rep) {
    const int id = rep * 128 + tid;       // 0..1023
    const int d  = id >> 4;               // 0..63
    const int q4 = (id & 15) * 4;
    const float4_t f = *(const float4_t*)&qg[qb + (size_t)d * SEQ + (size_t)(q0 + q4)];
    SM[(q4 + 0) * 68 + d] = f2bf1(c * f[0]);
    SM[(q4 + 1) * 68 + d] = f2bf1(c * f[1]);
    SM[(q4 + 2) * 68 + d] = f2bf1(c * f[2]);
    SM[(q4 + 3) * 68 + d] = f2bf1(c * f[3]);
  }
  __syncthreads();

  // Q B-fragments: B[kk=d=s*32+quad*8+j][n=q=l16], groups g=0,1 (q=w*32+g*16+l16)
  short8_t qfrag[2][2];
#pragma unroll
  for (int g = 0; g < 2; ++g)
#pragma unroll
    for (int s = 0; s < 2; ++s) {
      const short* qp = &SM[(w * 32 + g * 16 + l16) * 68 + s * 32 + quad * 8];
      const short4_t lo = *(const short4_t*)qp;
      const short4_t hi = *(const short4_t*)(qp + 4);
      qfrag[g][s] = short8_t{lo[0], lo[1], lo[2], lo[3], hi[0], hi[1], hi[2], hi[3]};
    }
  __syncthreads();  // Q reads done before DMA overwrites SM

  // ---- DMA setup: tiles contiguous 8 KB; wave w covers 1KB-instrs w*4..w*4+3 ----
  const char* ksrc = (const char*)Kt2 + (size_t)bh * NKT * 8192 + w * 4096 + lane * 16;
  const char* vsrc = (const char*)Vt2 + (size_t)bh * NKT * 8192 + w * 4096 + lane * 16;
  short* const kdst = &SM[w * 2048 + lane * 8];
  short* const vdst = &SM[8192 + w * 2048 + lane * 8];

  // loop-invariant fragment base pointers (parity/s/t/tt via immediates)
  const short* const kfp = &SM[quad * 512 + l16 * 8];          // + par + s*2048 + t*128
  const short* const vfp = &SM[8192 + quad * 256 + l16 * 4];   // + par + t*1024 + tt*64

  const float4_t z4 = {0.f, 0.f, 0.f, 0.f};
  float4_t oacc[2][4];
#pragma unroll
  for (int g = 0; g < 2; ++g)
#pragma unroll
    for (int tt = 0; tt < 4; ++tt) oacc[g][tt] = z4;
  float4_t lacc[2] = {z4, z4};
  const short one_bf = (short)0x3F80;
  const short4_t ones4 = (l16 == 0) ? short4_t{one_bf, one_bf, one_bf, one_bf}
                                    : short4_t{0, 0, 0, 0};

  // ---- prologue: DMA tile 0 -> parity 0 ----
#pragma unroll
  for (int i = 0; i < 4; ++i) gld16(ksrc + i * 1024, kdst + i * 512);
#pragma unroll
  for (int i = 0; i < 4; ++i) gld16(vsrc + i * 1024, vdst + i * 512);
  size_t goff = 8192;

#pragma unroll 2
  for (int kt = 0; kt < NKT; ++kt) {
    __syncthreads();  // vmcnt(0) drain + barrier: tile kt live

    if (kt < NKT - 1) {
      const int pn = ((kt + 1) & 1) * 4096;
#pragma unroll
      for (int i = 0; i < 4; ++i) gld16(ksrc + goff + i * 1024, kdst + pn + i * 512);
#pragma unroll
      for (int i = 0; i < 4; ++i) gld16(vsrc + goff + i * 1024, vdst + pn + i * 512);
      goff += 8192;
    }
    const int par = (kt & 1) * 4096;

    // ---- S^T = K^T * Q : 8 K b128 reads, 16 mfma32 (each read -> 2 groups) ----
    float4_t sac[2][4];
#pragma unroll
    for (int t = 0; t < 4; ++t) {
      const short8_t kv = *(const short8_t*)(kfp + par + t * 128);
      sac[0][t] = mfma32(kv, qfrag[0][0], z4);
      sac[1][t] = mfma32(kv, qfrag[1][0], z4);
    }
#pragma unroll
    for (int t = 0; t < 4; ++t) {
      const short8_t kv = *(const short8_t*)(kfp + par + 2048 + t * 128);
      sac[0][t] = mfma32(kv, qfrag[0][1], sac[0][t]);
      sac[1][t] = mfma32(kv, qfrag[1][1], sac[1][t]);
    }

    // ---- p = exp2(s); P C-layout == B-layout of 16x16x16; lsum via ones-MFMA ----
    short4_t pbf[2][4];
#pragma unroll
    for (int g = 0; g < 2; ++g)
#pragma unroll
      for (int t = 0; t < 4; ++t) {
        const float e0 = fast_exp2(sac[g][t][0]);
        const float e1 = fast_exp2(sac[g][t][1]);
        const float e2 = fast_exp2(sac[g][t][2]);
        const float e3 = fast_exp2(sac[g][t][3]);
        union { short4_t s; unsigned u[2]; } p;
        p.u[0] = f2bf2u(e0, e1);
        p.u[1] = f2bf2u(e2, e3);
        pbf[g][t] = p.s;
        lacc[g] = mfma16(ones4, pbf[g][t], lacc[g]);
      }

    // ---- O^T += V * P^T : 16 V b64 reads, 32 mfma16 (each read -> 2 groups) ----
#pragma unroll
    for (int t = 0; t < 4; ++t) {
      const short* vfb = vfp + par + t * 1024;
#pragma unroll
      for (int tt = 0; tt < 4; ++tt) {
        const short4_t vv = *(const short4_t*)(vfb + tt * 64);
        oacc[0][tt] = mfma16(vv, pbf[0][t], oacc[0][tt]);
        oacc[1][tt] = mfma16(vv, pbf[1][t], oacc[1][tt]);
      }
    }
  }

  // ---- epilogue: lsum at quad0/reg0 col=l16 -> broadcast, normalize, store ----
#pragma unroll
  for (int g = 0; g < 2; ++g) {
    const float ls  = __shfl(lacc[g][0], l16, 64);
    const float inv = 1.0f / ls;
    const size_t ob = qb + (size_t)(q0 + w * 32 + g * 16 + l16);
#pragma unroll
    for (int tt = 0; tt < 4; ++tt)
#pragma unroll
      for (int r = 0; r < 4; ++r)
        outg[ob + (size_t)(tt * 16 + quad * 4 + r) * SEQ] = oacc[g][tt][r] * inv;
  }
}

// ---------------- fallback (ws too small): R2-style, known-good ----------------
#define DPAD  72
#define PPAD  68
__global__ __launch_bounds__(256, 5)
void eia_attn_fb(const float* __restrict__ qg, const float* __restrict__ kg,
                 const float* __restrict__ vg, const int* __restrict__ klen,
                 float* __restrict__ outg) {
  __shared__ __align__(16) short QPs[64 * DPAD];
  __shared__ __align__(16) short Ksf[64 * DPAD];
  __shared__ __align__(16) short Vsf[64 * DPAD];

  const int tid  = threadIdx.x;
  const int bh   = blockIdx.x & 31;
  const int qt   = blockIdx.x >> 5;
  const int q0   = qt * 64;
  const int w    = tid >> 6;
  const int lane = tid & 63;
  const int quad = lane >> 4;
  const int l16  = lane & 15;

  const size_t base = (size_t)bh * 64 * SEQ;
  const float c = (1.4426950408889634f / (8.0f * 2.9957322735539909f)) *
                  logf((float)klen[bh >> 3]);

#pragma unroll
  for (int it = 0; it < 2; ++it) {
    const int e = it * 4 + w;
    float f[8];
#pragma unroll
    for (int j = 0; j < 8; ++j)
      f[j] = c * qg[base + (size_t)(e * 8 + j) * SEQ + (size_t)(q0 + lane)];
    union { short8_t s8; unsigned u[4]; } t;
#pragma unroll
    for (int j = 0; j < 4; ++j) t.u[j] = f2bf2u(f[2 * j], f[2 * j + 1]);
    *(short8_t*)&QPs[lane * DPAD + e * 8] = t.s8;
  }
  __syncthreads();

  short8_t qfrag[2];
#pragma unroll
  for (int s = 0; s < 2; ++s)
    qfrag[s] = *(const short8_t*)&QPs[(w * 16 + l16) * DPAD + s * 32 + quad * 8];

  float4_t oacc[4];
#pragma unroll
  for (int t = 0; t < 4; ++t) { oacc[t][0] = 0.f; oacc[t][1] = 0.f; oacc[t][2] = 0.f; oacc[t][3] = 0.f; }
  float lsumv[4] = {0.f, 0.f, 0.f, 0.f};
  const int pbase = w * (16 * DPAD);

  for (int kt = 0; kt < NKT; ++kt) {
    const int k0 = kt * 64;
#pragma unroll
    for (int it = 0; it < 2; ++it) {
      float f[8];
#pragma unroll
      for (int j = 0; j < 8; ++j)
        f[j] = kg[base + (size_t)((it * 4 + w) * 8 + j) * SEQ + (size_t)(k0 + lane)];
      union { short8_t s8; unsigned u[4]; } t;
#pragma unroll
      for (int j = 0; j < 4; ++j) t.u[j] = f2bf2u(f[2 * j], f[2 * j + 1]);
      *(short8_t*)&Ksf[lane * DPAD + (it * 4 + w) * 8] = t.s8;
    }
#pragma unroll
    for (int it = 0; it < 4; ++it) {
      const int d = it * 16 + (w << 2) + (lane >> 4);
      const float4_t vv = *(const float4_t*)&vg[base + (size_t)d * SEQ + (size_t)(k0 + ((lane & 15) << 2))];
      union { short4_t s4; unsigned u[2]; } t;
      t.u[0] = f2bf2u(vv[0], vv[1]);
      t.u[1] = f2bf2u(vv[2], vv[3]);
      *(short4_t*)&Vsf[d * DPAD + ((lane & 15) << 2)] = t.s4;
    }
    __syncthreads();

    float4_t sacc[4];
#pragma unroll
    for (int t = 0; t < 4; ++t) { sacc[t][0] = 0.f; sacc[t][1] = 0.f; sacc[t][2] = 0.f; sacc[t][3] = 0.f; }
#pragma unroll
    for (int t = 0; t < 4; ++t)
#pragma unroll
      for (int s = 0; s < 2; ++s) {
        const short8_t bf = *(const short8_t*)&Ksf[(t * 16 + l16) * DPAD + s * 32 + quad * 8];
        sacc[t] = mfma32(qfrag[s], bf, sacc[t]);
      }

#pragma unroll
    for (int r = 0; r < 4; ++r) {
      const float p0 = fast_exp2(sacc[0][r]);
      const float p1 = fast_exp2(sacc[1][r]);
      const float p2 = fast_exp2(sacc[2][r]);
      const float p3 = fast_exp2(sacc[3][r]);
      lsumv[r] += (p0 + p1) + (p2 + p3);
      const int prow = pbase + (quad * 4 + r) * PPAD + l16;
      QPs[prow +  0] = f2bf1(p0);
      QPs[prow + 16] = f2bf1(p1);
      QPs[prow + 32] = f2bf1(p2);
      QPs[prow + 48] = f2bf1(p3);
    }

#pragma unroll
    for (int s = 0; s < 2; ++s) {
      const short* pr = &QPs[pbase + l16 * PPAD + s * 32 + quad * 8];
      const short4_t plo = *(const short4_t*)pr;
      const short4_t phi = *(const short4_t*)(pr + 4);
      const short8_t pf = {plo[0], plo[1], plo[2], plo[3], phi[0], phi[1], phi[2], phi[3]};
#pragma unroll
      for (int t = 0; t < 4; ++t) {
        const short8_t vf = *(const short8_t*)&Vsf[(t * 16 + l16) * DPAD + s * 32 + quad * 8];
        oacc[t] = mfma32(pf, vf, oacc[t]);
      }
    }
    __syncthreads();
  }

  float inv[4];
#pragma unroll
  for (int r = 0; r < 4; ++r) {
    float v = lsumv[r];
    v += __shfl_xor(v, 1);
    v += __shfl_xor(v, 2);
    v += __shfl_xor(v, 4);
    v += __shfl_xor(v, 8);
    inv[r] = 1.0f / v;
  }
#pragma unroll
  for (int t = 0; t < 4; ++t)
#pragma unroll
    for (int r = 0; r < 4; ++r)
      outg[base + (size_t)(t * 16 + l16) * SEQ +
           (size_t)(q0 + w * 16 + quad * 4 + r)] = oacc[t][r] * inv[r];
}

extern "C" void kernel_launch(void* const* d_in, const int* in_sizes, int n_in,
                              void* d_out, int out_size, void* d_ws, size_t ws_size,
                              hipStream_t stream) {
  const float* q  = (const float*)d_in[0];
  const float* k  = (const float*)d_in[1];
  const float* v  = (const float*)d_in[2];
  const int*   kl = (const int*)d_in[3];
  float* out = (float*)d_out;

  const size_t TEN  = (size_t)NBH * SEQ * 64;
  const size_t need = 2 * TEN * sizeof(unsigned short);  // 16.8 MB

  if (ws_size >= need) {
    unsigned short* Kt2 = (unsigned short*)d_ws;
    unsigned short* Vt2 = Kt2 + TEN;
    eia_prep_kernel<<<2048, 256, 0, stream>>>(k, v, Kt2, Vt2);
    eia_attn_kernel<<<1024, 128, 0, stream>>>(q, Kt2, Vt2, kl, out);
  } else {
    eia_attn_fb<<<1024, 256, 0, stream>>>(q, k, v, kl, out);
  }
}

// Round 6
// 139.786 us; speedup vs baseline: 1.0753x; 1.0753x over previous
//
#include <hip/hip_runtime.h>
#include <hip/hip_bf16.h>
#include <math.h>

// EntropyInvarianceAttention: out = softmax(c * Q^T K) V^T per (b,h),
// c = ln(k_length[b]) / (8*ln(20)); q,k,v are (B, 512, 2048) fp32, l contiguous.
//
// R6 = R4 shape (256 thr, TQ=128, 512 blocks; layouts measured conflict-free)
// + software pipeline that keeps prefetch loads in flight ACROSS the barrier:
//  - 3-stage LDS (48 KB = 3 x {K 8KB + V 8KB}), prefetch distance 2
//  - raw `s_waitcnt vmcnt(4)` + raw `s_barrier` instead of __syncthreads():
//    waits only the current tile's 4 DMA loads, leaves next tile's 4 in flight
//    (AITER-style fine vmcnt; __syncthreads' vmcnt(0) drain was the stall).
//  - last iteration peeled with vmcnt(0).
// Per wave per tile: 4x global_load_lds(16B). Stage hazard: stage (kt+2)%3 is
// rewritten only after the barrier proving all waves finished iter kt-1, and
// all ds_reads of an iter are consumed by MFMAs issued pre-barrier (compiler
// lgkmcnt waits) -> no read-after-overwrite race.

typedef __attribute__((ext_vector_type(8))) short short8_t;
typedef __attribute__((ext_vector_type(4))) short short4_t;
typedef __attribute__((ext_vector_type(4))) float float4_t;

#define SEQ   2048
#define NBH   32
#define NKT   32

__device__ __forceinline__ unsigned f2bf2u(float a, float b) {
#if __has_builtin(__builtin_amdgcn_cvt_pk_bf16_f32)
  typedef __bf16 bf16x2_t __attribute__((ext_vector_type(2)));
  union { bf16x2_t v; unsigned u; } cv;
  cv.v = __builtin_amdgcn_cvt_pk_bf16_f32(a, b);
  return cv.u;
#else
  union { float f; unsigned u; } x, y;
  x.f = a; y.f = b;
  unsigned ra = x.u + 0x7fffu + ((x.u >> 16) & 1u);
  unsigned rb = y.u + 0x7fffu + ((y.u >> 16) & 1u);
  return (ra >> 16) | (rb & 0xffff0000u);
#endif
}

__device__ __forceinline__ short f2bf1(float a) {
  return (short)(f2bf2u(a, a) & 0xffffu);
}

__device__ __forceinline__ float fast_exp2(float x) {
#if __has_builtin(__builtin_amdgcn_exp2f)
  return __builtin_amdgcn_exp2f(x);
#else
  return exp2f(x);
#endif
}

__device__ __forceinline__ void gld16(const void* g, void* l) {
  __builtin_amdgcn_global_load_lds(
      (const __attribute__((address_space(1))) void*)g,
      (__attribute__((address_space(3))) void*)l, 16, 0, 0);
}

__device__ __forceinline__ float4_t mfma32(short8_t a, short8_t b, float4_t c) {
  return __builtin_amdgcn_mfma_f32_16x16x32_bf16(a, b, c, 0, 0, 0);
}

__device__ __forceinline__ float4_t mfma16(short4_t a, short4_t b, float4_t c) {
#if __has_builtin(__builtin_amdgcn_mfma_f32_16x16x16bf16_1k)
  return __builtin_amdgcn_mfma_f32_16x16x16bf16_1k(a, b, c, 0, 0, 0);
#else
  asm("v_mfma_f32_16x16x16_bf16 %0, %1, %2, %0" : "+v"(c) : "v"(a), "v"(b));
  return c;
#endif
}

// ---------------- fused pre-pass: K and V -> tile-blocked swizzled bf16 ----
// K -> Kt2[bh][kt][dc(8)][k(64)][8], V -> Vt2[bh][kt][k4(16)][d(64)][4].
// Tiles contiguous 8 KB; unchanged (layouts measured conflict-free in R4).
#define PST 68
__global__ __launch_bounds__(256, 8)
void eia_prep_kernel(const float* __restrict__ kg, const float* __restrict__ vg,
                     unsigned short* __restrict__ Kt2, unsigned short* __restrict__ Vt2) {
  __shared__ __align__(16) short T[64 * PST];
  const int id  = blockIdx.x;
  const int isV = id >> 10;
  const int sub = id & 1023;
  const int bh  = sub >> 5;
  const int kt  = sub & 31;
  const int t   = threadIdx.x;

  if (!isV) {
    const size_t ib = ((size_t)bh * 64) * SEQ + (size_t)(kt * 64) + (t & 63);
    const int dg = t >> 6;
#pragma unroll
    for (int dd = 0; dd < 16; dd += 4) {
      const int d = dg * 16 + dd;
      const float f0 = kg[ib + (size_t)(d + 0) * SEQ];
      const float f1 = kg[ib + (size_t)(d + 1) * SEQ];
      const float f2 = kg[ib + (size_t)(d + 2) * SEQ];
      const float f3 = kg[ib + (size_t)(d + 3) * SEQ];
      union { short4_t s; unsigned u[2]; } p;
      p.u[0] = f2bf2u(f0, f1);
      p.u[1] = f2bf2u(f2, f3);
      *(short4_t*)&T[(t & 63) * PST + d] = p.s;
    }
    __syncthreads();
    unsigned short* outt = Kt2 + (size_t)(bh * 32 + kt) * 4096;
#pragma unroll
    for (int rep = 0; rep < 2; ++rep) {
      const int id2 = rep * 256 + t;
      const int lr = id2 & 63, ch = id2 >> 6;
      union { short8_t v; short4_t h[2]; } o;
      o.h[0] = *(const short4_t*)&T[lr * PST + ch * 8];
      o.h[1] = *(const short4_t*)&T[lr * PST + ch * 8 + 4];
      *(short8_t*)&outt[ch * 512 + lr * 8] = o.v;
    }
  } else {
#pragma unroll
    for (int rep = 0; rep < 4; ++rep) {
      const int id2 = rep * 256 + t;
      const int d = id2 >> 4, l4 = (id2 & 15) * 4;
      const float4_t f = *(const float4_t*)&vg[((size_t)bh * 64 + d) * SEQ + kt * 64 + l4];
      union { short4_t s; unsigned u[2]; } p;
      p.u[0] = f2bf2u(f[0], f[1]);
      p.u[1] = f2bf2u(f[2], f[3]);
      *(short4_t*)&T[d * PST + l4] = p.s;
    }
    __syncthreads();
    unsigned short* outt = Vt2 + (size_t)(bh * 32 + kt) * 4096;
#pragma unroll
    for (int rep = 0; rep < 2; ++rep) {
      const int c = rep * 256 + t;
      const int k4 = c >> 5, dp = c & 31;
      union { short8_t v; short4_t h[2]; } o;
      o.h[0] = *(const short4_t*)&T[(2 * dp) * PST + k4 * 4];
      o.h[1] = *(const short4_t*)&T[(2 * dp + 1) * PST + k4 * 4];
      *(short8_t*)&outt[k4 * 256 + dp * 8] = o.v;
    }
  }
}

// ---------------- main fused attention ----------------
// LDS (shorts): K stages [0,4096)|[4096,8192)|[8192,12288)
//               V stages [12288,16384)|[16384,20480)|[20480,24576)
// Q staging overlays [0, 8704) before the first DMA.
__global__ __launch_bounds__(256, 2)
void eia_attn_kernel(const float* __restrict__ qg,
                     const unsigned short* __restrict__ Kt2,
                     const unsigned short* __restrict__ Vt2,
                     const int* __restrict__ klen,
                     float* __restrict__ outg) {
  __shared__ __align__(16) short SM[24576];

  const int tid  = threadIdx.x;
  const int bh   = blockIdx.x & 31;   // XCD = bh%8; 512 blocks = 2/CU
  const int qt   = blockIdx.x >> 5;
  const int q0   = qt * 128;
  const int w    = tid >> 6;          // wave 0..3
  const int lane = tid & 63;
  const int quad = lane >> 4;
  const int l16  = lane & 15;

  const float c = (1.4426950408889634f / (8.0f * 2.9957322735539909f)) *
                  logf((float)klen[bh >> 3]);
  const size_t qb = (size_t)bh * 64 * SEQ;

  // ---- Q stage: fp32 global -> SM[q][d] bf16 (stride 68), c folded ----
#pragma unroll
  for (int rep = 0; rep < 8; ++rep) {
    const int id = rep * 256 + tid;       // 0..2047
    const int d  = id >> 5;               // 0..63
    const int q4 = (id & 31) * 4;
    const float4_t f = *(const float4_t*)&qg[qb + (size_t)d * SEQ + (size_t)(q0 + q4)];
    SM[(q4 + 0) * 68 + d] = f2bf1(c * f[0]);
    SM[(q4 + 1) * 68 + d] = f2bf1(c * f[1]);
    SM[(q4 + 2) * 68 + d] = f2bf1(c * f[2]);
    SM[(q4 + 3) * 68 + d] = f2bf1(c * f[3]);
  }
  __syncthreads();

  // Q B-fragments: B[kk=d=s*32+quad*8+j][n=q=l16], groups g=0,1 (q=w*32+g*16+l16)
  short8_t qfrag[2][2];
#pragma unroll
  for (int g = 0; g < 2; ++g)
#pragma unroll
    for (int s = 0; s < 2; ++s) {
      const short* qp = &SM[(w * 32 + g * 16 + l16) * 68 + s * 32 + quad * 8];
      const short4_t lo = *(const short4_t*)qp;
      const short4_t hi = *(const short4_t*)(qp + 4);
      qfrag[g][s] = short8_t{lo[0], lo[1], lo[2], lo[3], hi[0], hi[1], hi[2], hi[3]};
    }
  __syncthreads();  // Q reads done before DMA overwrites SM

  // ---- DMA setup: tile = 8 x 1KB instrs; wave w covers instrs 2w, 2w+1 ----
  const char* ksrc = (const char*)Kt2 + (size_t)bh * NKT * 8192 + (2 * w) * 1024 + lane * 16;
  const char* vsrc = (const char*)Vt2 + (size_t)bh * NKT * 8192 + (2 * w) * 1024 + lane * 16;
  short* const kdst = &SM[(2 * w) * 512];            // + stage*4096 (HW adds lane*16B)
  short* const vdst = &SM[12288 + (2 * w) * 512];

  // loop-invariant fragment base pointers (stage via register offset)
  const short* const kfp = &SM[quad * 512 + l16 * 8];          // + koff + s*2048 + t*128
  const short* const vfp = &SM[12288 + quad * 256 + l16 * 4];  // + koff + t*1024 + tt*64

  const float4_t z4 = {0.f, 0.f, 0.f, 0.f};
  float4_t oacc[2][4];
#pragma unroll
  for (int g = 0; g < 2; ++g)
#pragma unroll
    for (int tt = 0; tt < 4; ++tt) oacc[g][tt] = z4;
  float4_t lacc[2] = {z4, z4};
  const short one_bf = (short)0x3F80;
  const short4_t ones4 = (l16 == 0) ? short4_t{one_bf, one_bf, one_bf, one_bf}
                                    : short4_t{0, 0, 0, 0};

  // ---- prologue: DMA tiles 0,1 -> stages 0,1 (4 loads/wave/tile) ----
  gld16(ksrc, kdst);              gld16(ksrc + 1024, kdst + 512);
  gld16(vsrc, vdst);              gld16(vsrc + 1024, vdst + 512);
  gld16(ksrc + 8192, kdst + 4096); gld16(ksrc + 8192 + 1024, kdst + 4096 + 512);
  gld16(vsrc + 8192, vdst + 4096); gld16(vsrc + 8192 + 1024, vdst + 4096 + 512);

  int  sc = 0;              // stage (shorts offset/4096) of current tile
  int  sn = 2;              // stage of tile kt+2
  size_t gsrc = 2 * 8192;   // byte offset of tile kt+2

  for (int kt = 0; kt < NKT; ++kt) {
    // wait: current tile's 4 loads done; NEXT tile's 4 stay in flight.
    if (kt < NKT - 1) asm volatile("s_waitcnt vmcnt(4)" ::: "memory");
    else              asm volatile("s_waitcnt vmcnt(0)" ::: "memory");
    asm volatile("s_barrier" ::: "memory");

    // issue DMA for tile kt+2 into stage sn (2 compute sections to land)
    if (kt < NKT - 2) {
      const int so = sn * 4096;
      gld16(ksrc + gsrc, kdst + so); gld16(ksrc + gsrc + 1024, kdst + so + 512);
      gld16(vsrc + gsrc, vdst + so); gld16(vsrc + gsrc + 1024, vdst + so + 512);
      gsrc += 8192;
      sn = (sn == 2) ? 0 : sn + 1;
    }
    const int koff = sc * 4096;
    sc = (sc == 2) ? 0 : sc + 1;
    const short* const kb = kfp + koff;
    const short* const vb = vfp + koff;

    // ---- S^T = K^T * Q : 8 K b128 reads, 16 mfma32 (each read -> 2 groups) ----
    float4_t sac[2][4];
#pragma unroll
    for (int t = 0; t < 4; ++t) {
      const short8_t kv = *(const short8_t*)(kb + t * 128);
      sac[0][t] = mfma32(kv, qfrag[0][0], z4);
      sac[1][t] = mfma32(kv, qfrag[1][0], z4);
    }
#pragma unroll
    for (int t = 0; t < 4; ++t) {
      const short8_t kv = *(const short8_t*)(kb + 2048 + t * 128);
      sac[0][t] = mfma32(kv, qfrag[0][1], sac[0][t]);
      sac[1][t] = mfma32(kv, qfrag[1][1], sac[1][t]);
    }

    // ---- p = exp2(s); P C-layout == B-layout of 16x16x16; lsum via ones-MFMA ----
    short4_t pbf[2][4];
#pragma unroll
    for (int g = 0; g < 2; ++g)
#pragma unroll
      for (int t = 0; t < 4; ++t) {
        const float e0 = fast_exp2(sac[g][t][0]);
        const float e1 = fast_exp2(sac[g][t][1]);
        const float e2 = fast_exp2(sac[g][t][2]);
        const float e3 = fast_exp2(sac[g][t][3]);
        union { short4_t s; unsigned u[2]; } p;
        p.u[0] = f2bf2u(e0, e1);
        p.u[1] = f2bf2u(e2, e3);
        pbf[g][t] = p.s;
        lacc[g] = mfma16(ones4, pbf[g][t], lacc[g]);
      }

    // ---- O^T += V * P^T : 16 V b64 reads, 32 mfma16 (each read -> 2 groups) ----
#pragma unroll
    for (int t = 0; t < 4; ++t) {
      const short* vfb = vb + t * 1024;
#pragma unroll
      for (int tt = 0; tt < 4; ++tt) {
        const short4_t vv = *(const short4_t*)(vfb + tt * 64);
        oacc[0][tt] = mfma16(vv, pbf[0][t], oacc[0][tt]);
        oacc[1][tt] = mfma16(vv, pbf[1][t], oacc[1][tt]);
      }
    }
  }

  // ---- epilogue: lsum at quad0/reg0 col=l16 -> broadcast, normalize, store ----
#pragma unroll
  for (int g = 0; g < 2; ++g) {
    const float ls  = __shfl(lacc[g][0], l16, 64);
    const float inv = 1.0f / ls;
    const size_t ob = qb + (size_t)(q0 + w * 32 + g * 16 + l16);
#pragma unroll
    for (int tt = 0; tt < 4; ++tt)
#pragma unroll
      for (int r = 0; r < 4; ++r)
        outg[ob + (size_t)(tt * 16 + quad * 4 + r) * SEQ] = oacc[g][tt][r] * inv;
  }
}

// ---------------- fallback (ws too small): R2-style, known-good ----------------
#define DPAD  72
#define PPAD  68
__global__ __launch_bounds__(256, 5)
void eia_attn_fb(const float* __restrict__ qg, const float* __restrict__ kg,
                 const float* __restrict__ vg, const int* __restrict__ klen,
                 float* __restrict__ outg) {
  __shared__ __align__(16) short QPs[64 * DPAD];
  __shared__ __align__(16) short Ksf[64 * DPAD];
  __shared__ __align__(16) short Vsf[64 * DPAD];

  const int tid  = threadIdx.x;
  const int bh   = blockIdx.x & 31;
  const int qt   = blockIdx.x >> 5;
  const int q0   = qt * 64;
  const int w    = tid >> 6;
  const int lane = tid & 63;
  const int quad = lane >> 4;
  const int l16  = lane & 15;

  const size_t base = (size_t)bh * 64 * SEQ;
  const float c = (1.4426950408889634f / (8.0f * 2.9957322735539909f)) *
                  logf((float)klen[bh >> 3]);

#pragma unroll
  for (int it = 0; it < 2; ++it) {
    const int e = it * 4 + w;
    float f[8];
#pragma unroll
    for (int j = 0; j < 8; ++j)
      f[j] = c * qg[base + (size_t)(e * 8 + j) * SEQ + (size_t)(q0 + lane)];
    union { short8_t s8; unsigned u[4]; } t;
#pragma unroll
    for (int j = 0; j < 4; ++j) t.u[j] = f2bf2u(f[2 * j], f[2 * j + 1]);
    *(short8_t*)&QPs[lane * DPAD + e * 8] = t.s8;
  }
  __syncthreads();

  short8_t qfrag[2];
#pragma unroll
  for (int s = 0; s < 2; ++s)
    qfrag[s] = *(const short8_t*)&QPs[(w * 16 + l16) * DPAD + s * 32 + quad * 8];

  float4_t oacc[4];
#pragma unroll
  for (int t = 0; t < 4; ++t) { oacc[t][0] = 0.f; oacc[t][1] = 0.f; oacc[t][2] = 0.f; oacc[t][3] = 0.f; }
  float lsumv[4] = {0.f, 0.f, 0.f, 0.f};
  const int pbase = w * (16 * DPAD);

  for (int kt = 0; kt < NKT; ++kt) {
    const int k0 = kt * 64;
#pragma unroll
    for (int it = 0; it < 2; ++it) {
      float f[8];
#pragma unroll
      for (int j = 0; j < 8; ++j)
        f[j] = kg[base + (size_t)((it * 4 + w) * 8 + j) * SEQ + (size_t)(k0 + lane)];
      union { short8_t s8; unsigned u[4]; } t;
#pragma unroll
      for (int j = 0; j < 4; ++j) t.u[j] = f2bf2u(f[2 * j], f[2 * j + 1]);
      *(short8_t*)&Ksf[lane * DPAD + (it * 4 + w) * 8] = t.s8;
    }
#pragma unroll
    for (int it = 0; it < 4; ++it) {
      const int d = it * 16 + (w << 2) + (lane >> 4);
      const float4_t vv = *(const float4_t*)&vg[base + (size_t)d * SEQ + (size_t)(k0 + ((lane & 15) << 2))];
      union { short4_t s4; unsigned u[2]; } t;
      t.u[0] = f2bf2u(vv[0], vv[1]);
      t.u[1] = f2bf2u(vv[2], vv[3]);
      *(short4_t*)&Vsf[d * DPAD + ((lane & 15) << 2)] = t.s4;
    }
    __syncthreads();

    float4_t sacc[4];
#pragma unroll
    for (int t = 0; t < 4; ++t) { sacc[t][0] = 0.f; sacc[t][1] = 0.f; sacc[t][2] = 0.f; sacc[t][3] = 0.f; }
#pragma unroll
    for (int t = 0; t < 4; ++t)
#pragma unroll
      for (int s = 0; s < 2; ++s) {
        const short8_t bf = *(const short8_t*)&Ksf[(t * 16 + l16) * DPAD + s * 32 + quad * 8];
        sacc[t] = mfma32(qfrag[s], bf, sacc[t]);
      }

#pragma unroll
    for (int r = 0; r < 4; ++r) {
      const float p0 = fast_exp2(sacc[0][r]);
      const float p1 = fast_exp2(sacc[1][r]);
      const float p2 = fast_exp2(sacc[2][r]);
      const float p3 = fast_exp2(sacc[3][r]);
      lsumv[r] += (p0 + p1) + (p2 + p3);
      const int prow = pbase + (quad * 4 + r) * PPAD + l16;
      QPs[prow +  0] = f2bf1(p0);
      QPs[prow + 16] = f2bf1(p1);
      QPs[prow + 32] = f2bf1(p2);
      QPs[prow + 48] = f2bf1(p3);
    }

#pragma unroll
    for (int s = 0; s < 2; ++s) {
      const short* pr = &QPs[pbase + l16 * PPAD + s * 32 + quad * 8];
      const short4_t plo = *(const short4_t*)pr;
      const short4_t phi = *(const short4_t*)(pr + 4);
      const short8_t pf = {plo[0], plo[1], plo[2], plo[3], phi[0], phi[1], phi[2], phi[3]};
#pragma unroll
      for (int t = 0; t < 4; ++t) {
        const short8_t vf = *(const short8_t*)&Vsf[(t * 16 + l16) * DPAD + s * 32 + quad * 8];
        oacc[t] = mfma32(pf, vf, oacc[t]);
      }
    }
    __syncthreads();
  }

  float inv[4];
#pragma unroll
  for (int r = 0; r < 4; ++r) {
    float v = lsumv[r];
    v += __shfl_xor(v, 1);
    v += __shfl_xor(v, 2);
    v += __shfl_xor(v, 4);
    v += __shfl_xor(v, 8);
    inv[r] = 1.0f / v;
  }
#pragma unroll
  for (int t = 0; t < 4; ++t)
#pragma unroll
    for (int r = 0; r < 4; ++r)
      outg[base + (size_t)(t * 16 + l16) * SEQ +
           (size_t)(q0 + w * 16 + quad * 4 + r)] = oacc[t][r] * inv[r];
}

extern "C" void kernel_launch(void* const* d_in, const int* in_sizes, int n_in,
                              void* d_out, int out_size, void* d_ws, size_t ws_size,
                              hipStream_t stream) {
  const float* q  = (const float*)d_in[0];
  const float* k  = (const float*)d_in[1];
  const float* v  = (const float*)d_in[2];
  const int*   kl = (const int*)d_in[3];
  float* out = (float*)d_out;

  const size_t TEN  = (size_t)NBH * SEQ * 64;
  const size_t need = 2 * TEN * sizeof(unsigned short);  // 16.8 MB

  if (ws_size >= need) {
    unsigned short* Kt2 = (unsigned short*)d_ws;
    unsigned short* Vt2 = Kt2 + TEN;
    eia_prep_kernel<<<2048, 256, 0, stream>>>(k, v, Kt2, Vt2);
    eia_attn_kernel<<<512, 256, 0, stream>>>(q, Kt2, Vt2, kl, out);
  } else {
    eia_attn_fb<<<1024, 256, 0, stream>>>(q, k, v, kl, out);
  }
}